// Round 11
// baseline (170.788 us; speedup 1.0000x reference)
//
#include <hip/hip_runtime.h>
#include <hip/hip_fp16.h>

#define LL 16384
#define HH 128
#define WW 128
#define CC 64
#define NH 8
#define EPSF 1e-7f
#define KVCHUNKS 32

typedef __attribute__((ext_vector_type(8))) _Float16 f16x8;
typedef __attribute__((ext_vector_type(4))) float f32x4;
typedef __attribute__((ext_vector_type(8))) unsigned short u16x8;

// ---------------- Kernel A: qkv 1x1 conv + bias (+relu on q,k) via MFMA hi/lo ----------
__global__ void qkv_kernel(const float* __restrict__ x, const float* __restrict__ w,
                           const float* __restrict__ bias,
                           float* __restrict__ q, float* __restrict__ k, float* __restrict__ v) {
    const int pix0 = blockIdx.x * 128;
    const int b    = blockIdx.y;
    const int sec  = blockIdx.z;
    const int tid  = threadIdx.x;
    const int lane = tid & 63;
    const int wv   = tid >> 6;

    __shared__ _Float16 xh[128][72], xl[128][72];
    __shared__ _Float16 wh[64][72],  wl[64][72];

    {
        const float* xb = x + (size_t)b * CC * LL + pix0;
        for (int idx = tid; idx < 64 * 128; idx += 256) {
            const int ci = idx >> 7;
            const int px = idx & 127;
            const float vv = xb[(size_t)ci * LL + px];
            const _Float16 h = (_Float16)vv;
            xh[px][ci] = h;
            xl[px][ci] = (_Float16)(vv - (float)h);
        }
    }
    {
        const float* wsec = w + (size_t)sec * 64 * 64;
        for (int idx = tid; idx < 64 * 64; idx += 256) {
            const int co = idx >> 6;
            const int ci = idx & 63;
            const float vv = wsec[co * 64 + ci];
            const _Float16 h = (_Float16)vv;
            wh[co][ci] = h;
            wl[co][ci] = (_Float16)(vv - (float)h);
        }
    }
    __syncthreads();

    f32x4 acc[4][2];
#pragma unroll
    for (int ct = 0; ct < 4; ++ct)
#pragma unroll
        for (int pt = 0; pt < 2; ++pt) acc[ct][pt] = (f32x4)0.f;

    const int g8 = (lane >> 4) * 8;
    const int rl = lane & 15;

#pragma unroll
    for (int ks = 0; ks < 2; ++ks) {
        const int kb = ks * 32 + g8;
        f16x8 ah[4], al[4], bh[2], bl[2];
#pragma unroll
        for (int ct = 0; ct < 4; ++ct) {
            ah[ct] = *(const f16x8*)&wh[ct * 16 + rl][kb];
            al[ct] = *(const f16x8*)&wl[ct * 16 + rl][kb];
        }
#pragma unroll
        for (int pt = 0; pt < 2; ++pt) {
            bh[pt] = *(const f16x8*)&xh[wv * 32 + pt * 16 + rl][kb];
            bl[pt] = *(const f16x8*)&xl[wv * 32 + pt * 16 + rl][kb];
        }
#pragma unroll
        for (int ct = 0; ct < 4; ++ct)
#pragma unroll
            for (int pt = 0; pt < 2; ++pt) {
                acc[ct][pt] = __builtin_amdgcn_mfma_f32_16x16x32_f16(ah[ct], bh[pt], acc[ct][pt], 0, 0, 0);
                acc[ct][pt] = __builtin_amdgcn_mfma_f32_16x16x32_f16(ah[ct], bl[pt], acc[ct][pt], 0, 0, 0);
                acc[ct][pt] = __builtin_amdgcn_mfma_f32_16x16x32_f16(al[ct], bh[pt], acc[ct][pt], 0, 0, 0);
            }
    }

    float* dst = (sec == 0) ? q : (sec == 1) ? k : v;
    const bool do_relu = (sec < 2);
#pragma unroll
    for (int ct = 0; ct < 4; ++ct) {
        const int co_b = ct * 16 + (lane >> 4) * 4;
#pragma unroll
        for (int pt = 0; pt < 2; ++pt) {
            const int px = pix0 + wv * 32 + pt * 16 + rl;
#pragma unroll
            for (int j = 0; j < 4; ++j) {
                const int co = co_b + j;
                float val = acc[ct][pt][j] + bias[sec * 64 + co];
                if (do_relu) val = fmaxf(val, 0.f);
                dst[((size_t)b * 64 + co) * LL + px] = val;
            }
        }
    }
}

// ---------------- Kernel B: KV/KS partials, K staged in LDS ----------------
__global__ void kv_kernel(const float* __restrict__ k, const float* __restrict__ v,
                          float* __restrict__ KVp) {
    const int chunk = blockIdx.x;
    const int h = blockIdx.y;
    const int b = blockIdx.z;
    const int tid = threadIdx.x;
    const int c  = tid >> 5;
    const int s  = tid & 31;
    const int half = s >> 4;
    const int sl   = s & 15;
    const int cpb  = half * 4;

    __shared__ float klds[8][6][130];

    {
        const float* kb = k + ((size_t)(b * 64) + 8 * h) * LL;
        for (int t = tid; t < 8 * 6 * 130; t += 256) {
            const int ch = t / 780;
            const int r1 = t - ch * 780;
            const int lr = r1 / 130;
            const int cx = r1 - lr * 130;
            const int gy = chunk * 4 + lr - 1;
            const int gx = cx - 1;
            const bool ok = (gy >= 0 && gy < HH && gx >= 0 && gx < WW);
            klds[ch][lr][cx] = ok ? kb[(size_t)ch * LL + gy * WW + gx] : 0.f;
        }
    }
    __syncthreads();

    const float* vb = v + ((size_t)(b * 64) + 8 * h + cpb) * LL;

    float kv4[9][4] = {{0.f}};
    float ks[9] = {0.f};

    for (int r = 0; r < 4; ++r) {
        const int y = chunk * 4 + r;
        for (int g = 0; g < 8; ++g) {
            const int col = g * 16 + sl;
            float vv[4];
#pragma unroll
            for (int cp = 0; cp < 4; ++cp) vv[cp] = vb[(size_t)cp * LL + y * WW + col];
            float k9[9];
#pragma unroll
            for (int dy = 0; dy < 3; ++dy)
#pragma unroll
                for (int dx = 0; dx < 3; ++dx)
                    k9[dy * 3 + dx] = klds[c][r + dy][col + dx];
#pragma unroll
            for (int p = 0; p < 9; ++p) {
                ks[p] += k9[p];
#pragma unroll
                for (int cp = 0; cp < 4; ++cp)
                    kv4[p][cp] = fmaf(k9[p], vv[cp], kv4[p][cp]);
            }
        }
    }

#pragma unroll
    for (int p = 0; p < 9; ++p) {
#pragma unroll
        for (int m = 8; m >= 1; m >>= 1) ks[p] += __shfl_xor(ks[p], m);
#pragma unroll
        for (int cp = 0; cp < 4; ++cp) {
#pragma unroll
            for (int m = 8; m >= 1; m >>= 1) kv4[p][cp] += __shfl_xor(kv4[p][cp], m);
        }
    }

    if (sl == 0) {
        float* dst = KVp + (((size_t)(b * NH + h) * KVCHUNKS) + chunk) * 648;
#pragma unroll
        for (int p = 0; p < 9; ++p) {
#pragma unroll
            for (int cp = 0; cp < 4; ++cp)
                dst[(c * 9 + p) * 8 + cpb + cp] = kv4[p][cp];
            if (half == 0) dst[576 + c * 9 + p] = ks[p];
        }
    }
}

// ---------------- Kernel B2: reduce 32 chunk-partials -> KV, KS ----------------
__global__ void kv_finalize(const float* __restrict__ KVp,
                            float* __restrict__ KV, float* __restrict__ KS) {
    const int bh = blockIdx.x;
    const float* src = KVp + (size_t)bh * KVCHUNKS * 648;
    for (int idx = threadIdx.x; idx < 648; idx += 256) {
        float s0 = 0.f, s1 = 0.f, s2 = 0.f, s3 = 0.f;
#pragma unroll
        for (int ch = 0; ch < KVCHUNKS; ch += 4) {
            s0 += src[(ch + 0) * 648 + idx];
            s1 += src[(ch + 1) * 648 + idx];
            s2 += src[(ch + 2) * 648 + idx];
            s3 += src[(ch + 3) * 648 + idx];
        }
        const float sum = (s0 + s1) + (s2 + s3);
        if (idx < 576) KV[(size_t)bh * 576 + idx] = sum;
        else           KS[(size_t)bh * 72 + (idx - 576)] = sum;
    }
}

// ---------------- Kernel C: attn, q staged in LDS, writes packed f16 hi/lo ----------
// grid (128 rows, NH, B), block 128 (thread = column)
__global__ void attn_kernel(const float* __restrict__ q, const float* __restrict__ KV,
                            const float* __restrict__ KS, unsigned int* __restrict__ aohl) {
    const int y = blockIdx.x;
    const int h = blockIdx.y;
    const int b = blockIdx.z;
    const int col = threadIdx.x;

    __shared__ float qlds[8][3][132];   // 8 ch x 3 rows x (128+2 halo), 12672 B

    {
        const float* qbase = q + ((size_t)(b * 64) + 8 * h) * LL;
        for (int t = threadIdx.x; t < 8 * 3 * 130; t += 128) {
            const int c  = t / 390;
            const int r1 = t - c * 390;
            const int lr = r1 / 130;
            const int cx = r1 - lr * 130;
            const int gy = y + lr - 1;
            const int gx = cx - 1;
            const bool ok = (gy >= 0 && gy < HH && gx >= 0 && gx < WW);
            qlds[c][lr][cx] = ok ? qbase[(size_t)c * LL + gy * WW + gx] : 0.f;
        }
    }
    __syncthreads();

    float out[8] = {0.f};
    float den = 0.f;
    const int kvbase = (b * NH + h) * 8;

    for (int c = 0; c < 8; ++c) {
        float q9[9];
#pragma unroll
        for (int dy = 0; dy < 3; ++dy)
#pragma unroll
            for (int dx = 0; dx < 3; ++dx)
                q9[dy * 3 + dx] = qlds[c][dy][col + dx];   // stride-1: conflict-free
        const float* kvr = KV + ((size_t)(kvbase + c) * 9) * 8;  // wave-uniform
        const float* ksr = KS + (size_t)(kvbase + c) * 9;
#pragma unroll
        for (int p = 0; p < 9; ++p) {
            const float qv = q9[p];
            den += qv * ksr[p];
#pragma unroll
            for (int cp = 0; cp < 8; ++cp) out[cp] += qv * kvr[p * 8 + cp];
        }
    }
    const float inv = 1.f / (den + EPSF);
    const int pix = y * WW + col;
#pragma unroll
    for (int cp = 0; cp < 8; ++cp) {
        const float val = out[cp] * inv;
        const _Float16 hf = (_Float16)val;
        const _Float16 lf = (_Float16)(val - (float)hf);
        unsigned short hb, lb;
        __builtin_memcpy(&hb, &hf, 2);
        __builtin_memcpy(&lb, &lf, 2);
        aohl[((size_t)(b * 64) + h * 8 + cp) * LL + pix] = (unsigned int)hb | ((unsigned int)lb << 16);
    }
}

// ---------------- Kernel W: pre-split proj_w into MFMA fragment layout ----------------
__global__ void wprep_kernel(const float* __restrict__ w, unsigned short* __restrict__ wfrag) {
    const int idx = blockIdx.x * 256 + threadIdx.x;   // 16*64*64 = 65536
    const int k  = idx & 63;
    const int co = (idx >> 6) & 63;
    const int ks = idx >> 12;
    const int kg = ks * 64 + k;
    const int ci = kg >> 4, tap = kg & 15;
    const float vv = (tap < 9) ? w[(co * 64 + ci) * 9 + tap] : 0.f;
    const _Float16 h = (_Float16)vv;
    const _Float16 l = (_Float16)(vv - (float)h);
    unsigned short hb, lb;
    __builtin_memcpy(&hb, &h, 2);
    __builtin_memcpy(&lb, &l, 2);
    const int kx = (((k >> 3) ^ (co & 7)) << 3) | (k & 7);
    wfrag[(((size_t)ks * 2 + 0) * 64 + co) * 64 + kx] = hb;
    wfrag[(((size_t)ks * 2 + 1) * 64 + co) * 64 + kx] = lb;
}

// ---------------- Kernel D: 3x3 conv via MFMA, reg-prefetch pipeline ----------------
// grid 1024 (XCD-chunk swizzled): block -> (row y, col-half, batch b), 64 pix.
// 16 ksteps of K=64 (4 ci). Wave wv owns pix [16wv,16wv+16); 4 co-tiles.
// T14 async-stage: next kstep's 9 P-u32 + 4 W-uint4 prefetched into regs,
// loads overlap the MFMA phase; LDS single-buffered (32 KB -> 4 blocks/CU by grid).
__global__ __launch_bounds__(256) void conv_kernel(const unsigned int* __restrict__ aohl,
                                                   const unsigned short* __restrict__ wfrag,
                                                   const float* __restrict__ bias,
                                                   float* __restrict__ out) {
    const int bid = blockIdx.x;
    const int swz = (bid & 7) * 128 + (bid >> 3);   // XCD-chunked
    const int b = swz >> 8;
    const int rem = swz & 255;
    const int y = rem >> 1;
    const int colbase = (rem & 1) * 64;
    const int tid = threadIdx.x;
    const int lane = tid & 63;
    const int wv = tid >> 6;
    const int rl = lane & 15;
    const int g  = lane >> 4;

    __shared__ unsigned short plds[2 * 64 * 64];   // 16384 B [hl][pix][k]
    __shared__ unsigned short wlds[2 * 64 * 64];   // 16384 B [hl][co][k]

    f32x4 acc[4];
#pragma unroll
    for (int ct = 0; ct < 4; ++ct) acc[ct] = (f32x4)0.f;

    const unsigned int* aob = aohl + (size_t)b * 64 * LL;
    const int spix = tid & 63;       // staging pixel (local)
    const int scis = tid >> 6;       // staging ci-select 0..3

    unsigned int p9[9];
    uint4 wreg[4];

    auto prefetch = [&](int ks) {
        const int ci = ks * 4 + scis;
        const unsigned int* src = aob + (size_t)ci * LL;
#pragma unroll
        for (int dy = 0; dy < 3; ++dy) {
            const int yy = y + dy - 1;
#pragma unroll
            for (int dx = 0; dx < 3; ++dx) {
                const int xx = colbase + spix + dx - 1;
                const bool ok = (yy >= 0 && yy < HH && xx >= 0 && xx < WW);
                p9[dy * 3 + dx] = ok ? src[yy * WW + xx] : 0u;
            }
        }
        const uint4* wsrc = (const uint4*)(wfrag + (size_t)ks * 8192);
#pragma unroll
        for (int i = 0; i < 4; ++i) wreg[i] = wsrc[i * 256 + tid];
    };

    prefetch(0);

    for (int ks = 0; ks < 16; ++ks) {
        __syncthreads();   // previous kstep's MFMA reads done
        // ---- write prefetched regs to LDS ----
        {
            unsigned short h16[16], l16[16];
#pragma unroll
            for (int j = 0; j < 16; ++j) {
                const unsigned int pv = (j < 9) ? p9[j] : 0u;
                h16[j] = (unsigned short)(pv & 0xffffu);
                l16[j] = (unsigned short)(pv >> 16);
            }
            const int x0 = (((2 * scis)     ^ (spix & 7)) << 3);
            const int x1 = (((2 * scis + 1) ^ (spix & 7)) << 3);
            *(u16x8*)&plds[(0 * 64 + spix) * 64 + x0] = *(u16x8*)&h16[0];
            *(u16x8*)&plds[(0 * 64 + spix) * 64 + x1] = *(u16x8*)&h16[8];
            *(u16x8*)&plds[(1 * 64 + spix) * 64 + x0] = *(u16x8*)&l16[0];
            *(u16x8*)&plds[(1 * 64 + spix) * 64 + x1] = *(u16x8*)&l16[8];
            uint4* wdst = (uint4*)&wlds[0];
#pragma unroll
            for (int i = 0; i < 4; ++i) wdst[i * 256 + tid] = wreg[i];
        }
        __syncthreads();
        if (ks < 15) prefetch(ks + 1);   // loads fly during MFMA phase

        // ---- MFMA: 2 ksubs x 4 co-tiles x 3 (hi/lo) ----
#pragma unroll
        for (int ksub = 0; ksub < 2; ++ksub) {
            const int xs = (((ksub * 4 + g) ^ (rl & 7)) << 3);
            const int row = wv * 16 + rl;
            const f16x8 bh = *(const f16x8*)&plds[(0 * 64 + row) * 64 + xs];
            const f16x8 bl = *(const f16x8*)&plds[(1 * 64 + row) * 64 + xs];
#pragma unroll
            for (int ct = 0; ct < 4; ++ct) {
                const int rowa = ct * 16 + rl;
                const f16x8 ah = *(const f16x8*)&wlds[(0 * 64 + rowa) * 64 + xs];
                const f16x8 al = *(const f16x8*)&wlds[(1 * 64 + rowa) * 64 + xs];
                acc[ct] = __builtin_amdgcn_mfma_f32_16x16x32_f16(ah, bh, acc[ct], 0, 0, 0);
                acc[ct] = __builtin_amdgcn_mfma_f32_16x16x32_f16(ah, bl, acc[ct], 0, 0, 0);
                acc[ct] = __builtin_amdgcn_mfma_f32_16x16x32_f16(al, bh, acc[ct], 0, 0, 0);
            }
        }
    }

#pragma unroll
    for (int ct = 0; ct < 4; ++ct) {
        const int co_b = ct * 16 + g * 4;
        const int px = colbase + wv * 16 + rl;
#pragma unroll
        for (int j = 0; j < 4; ++j) {
            const int co = co_b + j;
            out[((size_t)b * 64 + co) * LL + y * WW + px] = acc[ct][j] + bias[co];
        }
    }
}

extern "C" void kernel_launch(void* const* d_in, const int* in_sizes, int n_in,
                              void* d_out, int out_size, void* d_ws, size_t ws_size,
                              hipStream_t stream) {
    const float* x      = (const float*)d_in[0];
    const float* qkv_w  = (const float*)d_in[1];
    const float* qkv_b  = (const float*)d_in[2];
    const float* proj_w = (const float*)d_in[3];
    const float* proj_b = (const float*)d_in[4];
    float* out = (float*)d_out;
    float* ws  = (float*)d_ws;

    const size_t n1 = (size_t)4 * 64 * LL;      // one B*C*L plane set
    float* qb   = ws;
    float* kb   = ws + n1;
    float* vb   = ws + 2 * n1;
    unsigned int* aohl = (unsigned int*)(ws + 3 * n1);
    float* KV   = ws + 4 * n1;                  // 4*8*8*9*8 = 18432 floats
    float* KS   = KV + 4 * 8 * 8 * 9 * 8;       // 4*8*8*9  = 2304 floats
    float* KVp  = KS + 4 * 8 * 8 * 9;           // 32*32*648 = 663552 floats
    unsigned short* wfrag = (unsigned short*)(KVp + (size_t)32 * KVCHUNKS * 648);  // 131072 halfs

    wprep_kernel<<<256, 256, 0, stream>>>(proj_w, wfrag);
    qkv_kernel<<<dim3(128, 4, 3), 256, 0, stream>>>(x, qkv_w, qkv_b, qb, kb, vb);
    kv_kernel<<<dim3(KVCHUNKS, NH, 4), 256, 0, stream>>>(kb, vb, KVp);
    kv_finalize<<<32, 256, 0, stream>>>(KVp, KV, KS);
    attn_kernel<<<dim3(128, NH, 4), 128, 0, stream>>>(qb, KV, KS, aohl);
    conv_kernel<<<1024, 256, 0, stream>>>(aohl, wfrag, proj_b, out);
}

// Round 12
// 126.123 us; speedup vs baseline: 1.3541x; 1.3541x over previous
//
#include <hip/hip_runtime.h>
#include <hip/hip_fp16.h>

#define LL 16384
#define HH 128
#define WW 128
#define CC 64
#define NH 8
#define EPSF 1e-7f
#define KVCHUNKS 32

typedef __attribute__((ext_vector_type(8))) _Float16 f16x8;
typedef __attribute__((ext_vector_type(4))) float f32x4;
typedef __attribute__((ext_vector_type(8))) unsigned short u16x8;

// ---------------- Kernel A: qkv 1x1 conv + bias (+relu on q,k) via MFMA hi/lo ----------
__global__ void qkv_kernel(const float* __restrict__ x, const float* __restrict__ w,
                           const float* __restrict__ bias,
                           float* __restrict__ q, float* __restrict__ k, float* __restrict__ v) {
    const int pix0 = blockIdx.x * 128;
    const int b    = blockIdx.y;
    const int sec  = blockIdx.z;
    const int tid  = threadIdx.x;
    const int lane = tid & 63;
    const int wv   = tid >> 6;

    __shared__ _Float16 xh[128][72], xl[128][72];
    __shared__ _Float16 wh[64][72],  wl[64][72];

    {
        const float* xb = x + (size_t)b * CC * LL + pix0;
        for (int idx = tid; idx < 64 * 128; idx += 256) {
            const int ci = idx >> 7;
            const int px = idx & 127;
            const float vv = xb[(size_t)ci * LL + px];
            const _Float16 h = (_Float16)vv;
            xh[px][ci] = h;
            xl[px][ci] = (_Float16)(vv - (float)h);
        }
    }
    {
        const float* wsec = w + (size_t)sec * 64 * 64;
        for (int idx = tid; idx < 64 * 64; idx += 256) {
            const int co = idx >> 6;
            const int ci = idx & 63;
            const float vv = wsec[co * 64 + ci];
            const _Float16 h = (_Float16)vv;
            wh[co][ci] = h;
            wl[co][ci] = (_Float16)(vv - (float)h);
        }
    }
    __syncthreads();

    f32x4 acc[4][2];
#pragma unroll
    for (int ct = 0; ct < 4; ++ct)
#pragma unroll
        for (int pt = 0; pt < 2; ++pt) acc[ct][pt] = (f32x4)0.f;

    const int g8 = (lane >> 4) * 8;
    const int rl = lane & 15;

#pragma unroll
    for (int ks = 0; ks < 2; ++ks) {
        const int kb = ks * 32 + g8;
        f16x8 ah[4], al[4], bh[2], bl[2];
#pragma unroll
        for (int ct = 0; ct < 4; ++ct) {
            ah[ct] = *(const f16x8*)&wh[ct * 16 + rl][kb];
            al[ct] = *(const f16x8*)&wl[ct * 16 + rl][kb];
        }
#pragma unroll
        for (int pt = 0; pt < 2; ++pt) {
            bh[pt] = *(const f16x8*)&xh[wv * 32 + pt * 16 + rl][kb];
            bl[pt] = *(const f16x8*)&xl[wv * 32 + pt * 16 + rl][kb];
        }
#pragma unroll
        for (int ct = 0; ct < 4; ++ct)
#pragma unroll
            for (int pt = 0; pt < 2; ++pt) {
                acc[ct][pt] = __builtin_amdgcn_mfma_f32_16x16x32_f16(ah[ct], bh[pt], acc[ct][pt], 0, 0, 0);
                acc[ct][pt] = __builtin_amdgcn_mfma_f32_16x16x32_f16(ah[ct], bl[pt], acc[ct][pt], 0, 0, 0);
                acc[ct][pt] = __builtin_amdgcn_mfma_f32_16x16x32_f16(al[ct], bh[pt], acc[ct][pt], 0, 0, 0);
            }
    }

    float* dst = (sec == 0) ? q : (sec == 1) ? k : v;
    const bool do_relu = (sec < 2);
#pragma unroll
    for (int ct = 0; ct < 4; ++ct) {
        const int co_b = ct * 16 + (lane >> 4) * 4;
#pragma unroll
        for (int pt = 0; pt < 2; ++pt) {
            const int px = pix0 + wv * 32 + pt * 16 + rl;
#pragma unroll
            for (int j = 0; j < 4; ++j) {
                const int co = co_b + j;
                float val = acc[ct][pt][j] + bias[sec * 64 + co];
                if (do_relu) val = fmaxf(val, 0.f);
                dst[((size_t)b * 64 + co) * LL + px] = val;
            }
        }
    }
}

// ---------------- Kernel B: KV/KS partials, K staged in LDS ----------------
__global__ void kv_kernel(const float* __restrict__ k, const float* __restrict__ v,
                          float* __restrict__ KVp) {
    const int chunk = blockIdx.x;
    const int h = blockIdx.y;
    const int b = blockIdx.z;
    const int tid = threadIdx.x;
    const int c  = tid >> 5;
    const int s  = tid & 31;
    const int half = s >> 4;
    const int sl   = s & 15;
    const int cpb  = half * 4;

    __shared__ float klds[8][6][130];

    {
        const float* kb = k + ((size_t)(b * 64) + 8 * h) * LL;
        for (int t = tid; t < 8 * 6 * 130; t += 256) {
            const int ch = t / 780;
            const int r1 = t - ch * 780;
            const int lr = r1 / 130;
            const int cx = r1 - lr * 130;
            const int gy = chunk * 4 + lr - 1;
            const int gx = cx - 1;
            const bool ok = (gy >= 0 && gy < HH && gx >= 0 && gx < WW);
            klds[ch][lr][cx] = ok ? kb[(size_t)ch * LL + gy * WW + gx] : 0.f;
        }
    }
    __syncthreads();

    const float* vb = v + ((size_t)(b * 64) + 8 * h + cpb) * LL;

    float kv4[9][4] = {{0.f}};
    float ks[9] = {0.f};

    for (int r = 0; r < 4; ++r) {
        const int y = chunk * 4 + r;
        for (int g = 0; g < 8; ++g) {
            const int col = g * 16 + sl;
            float vv[4];
#pragma unroll
            for (int cp = 0; cp < 4; ++cp) vv[cp] = vb[(size_t)cp * LL + y * WW + col];
            float k9[9];
#pragma unroll
            for (int dy = 0; dy < 3; ++dy)
#pragma unroll
                for (int dx = 0; dx < 3; ++dx)
                    k9[dy * 3 + dx] = klds[c][r + dy][col + dx];
#pragma unroll
            for (int p = 0; p < 9; ++p) {
                ks[p] += k9[p];
#pragma unroll
                for (int cp = 0; cp < 4; ++cp)
                    kv4[p][cp] = fmaf(k9[p], vv[cp], kv4[p][cp]);
            }
        }
    }

#pragma unroll
    for (int p = 0; p < 9; ++p) {
#pragma unroll
        for (int m = 8; m >= 1; m >>= 1) ks[p] += __shfl_xor(ks[p], m);
#pragma unroll
        for (int cp = 0; cp < 4; ++cp) {
#pragma unroll
            for (int m = 8; m >= 1; m >>= 1) kv4[p][cp] += __shfl_xor(kv4[p][cp], m);
        }
    }

    if (sl == 0) {
        float* dst = KVp + (((size_t)(b * NH + h) * KVCHUNKS) + chunk) * 648;
#pragma unroll
        for (int p = 0; p < 9; ++p) {
#pragma unroll
            for (int cp = 0; cp < 4; ++cp)
                dst[(c * 9 + p) * 8 + cpb + cp] = kv4[p][cp];
            if (half == 0) dst[576 + c * 9 + p] = ks[p];
        }
    }
}

// ---------------- Kernel B2: reduce 32 chunk-partials -> KV, KS ----------------
__global__ void kv_finalize(const float* __restrict__ KVp,
                            float* __restrict__ KV, float* __restrict__ KS) {
    const int bh = blockIdx.x;
    const float* src = KVp + (size_t)bh * KVCHUNKS * 648;
    for (int idx = threadIdx.x; idx < 648; idx += 256) {
        float s0 = 0.f, s1 = 0.f, s2 = 0.f, s3 = 0.f;
#pragma unroll
        for (int ch = 0; ch < KVCHUNKS; ch += 4) {
            s0 += src[(ch + 0) * 648 + idx];
            s1 += src[(ch + 1) * 648 + idx];
            s2 += src[(ch + 2) * 648 + idx];
            s3 += src[(ch + 3) * 648 + idx];
        }
        const float sum = (s0 + s1) + (s2 + s3);
        if (idx < 576) KV[(size_t)bh * 576 + idx] = sum;
        else           KS[(size_t)bh * 72 + (idx - 576)] = sum;
    }
}

// ---------------- Kernel C: attn, q staged in LDS, writes packed f16 hi/lo ----------
__global__ void attn_kernel(const float* __restrict__ q, const float* __restrict__ KV,
                            const float* __restrict__ KS, unsigned int* __restrict__ aohl) {
    const int y = blockIdx.x;
    const int h = blockIdx.y;
    const int b = blockIdx.z;
    const int col = threadIdx.x;

    __shared__ float qlds[8][3][132];

    {
        const float* qbase = q + ((size_t)(b * 64) + 8 * h) * LL;
        for (int t = threadIdx.x; t < 8 * 3 * 130; t += 128) {
            const int c  = t / 390;
            const int r1 = t - c * 390;
            const int lr = r1 / 130;
            const int cx = r1 - lr * 130;
            const int gy = y + lr - 1;
            const int gx = cx - 1;
            const bool ok = (gy >= 0 && gy < HH && gx >= 0 && gx < WW);
            qlds[c][lr][cx] = ok ? qbase[(size_t)c * LL + gy * WW + gx] : 0.f;
        }
    }
    __syncthreads();

    float out[8] = {0.f};
    float den = 0.f;
    const int kvbase = (b * NH + h) * 8;

    for (int c = 0; c < 8; ++c) {
        float q9[9];
#pragma unroll
        for (int dy = 0; dy < 3; ++dy)
#pragma unroll
            for (int dx = 0; dx < 3; ++dx)
                q9[dy * 3 + dx] = qlds[c][dy][col + dx];
        const float* kvr = KV + ((size_t)(kvbase + c) * 9) * 8;
        const float* ksr = KS + (size_t)(kvbase + c) * 9;
#pragma unroll
        for (int p = 0; p < 9; ++p) {
            const float qv = q9[p];
            den += qv * ksr[p];
#pragma unroll
            for (int cp = 0; cp < 8; ++cp) out[cp] += qv * kvr[p * 8 + cp];
        }
    }
    const float inv = 1.f / (den + EPSF);
    const int pix = y * WW + col;
#pragma unroll
    for (int cp = 0; cp < 8; ++cp) {
        const float val = out[cp] * inv;
        const _Float16 hf = (_Float16)val;
        const _Float16 lf = (_Float16)(val - (float)hf);
        unsigned short hb, lb;
        __builtin_memcpy(&hb, &hf, 2);
        __builtin_memcpy(&lb, &lf, 2);
        aohl[((size_t)(b * 64) + h * 8 + cp) * LL + pix] = (unsigned int)hb | ((unsigned int)lb << 16);
    }
}

// ---------------- Kernel W: pre-split proj_w into MFMA fragment layout ----------------
__global__ void wprep_kernel(const float* __restrict__ w, unsigned short* __restrict__ wfrag) {
    const int idx = blockIdx.x * 256 + threadIdx.x;   // 16*64*64 = 65536
    const int k  = idx & 63;
    const int co = (idx >> 6) & 63;
    const int ks = idx >> 12;
    const int kg = ks * 64 + k;
    const int ci = kg >> 4, tap = kg & 15;
    const float vv = (tap < 9) ? w[(co * 64 + ci) * 9 + tap] : 0.f;
    const _Float16 h = (_Float16)vv;
    const _Float16 l = (_Float16)(vv - (float)h);
    unsigned short hb, lb;
    __builtin_memcpy(&hb, &h, 2);
    __builtin_memcpy(&lb, &l, 2);
    const int kx = (((k >> 3) ^ (co & 7)) << 3) | (k & 7);
    wfrag[(((size_t)ks * 2 + 0) * 64 + co) * 64 + kx] = hb;
    wfrag[(((size_t)ks * 2 + 1) * 64 + co) * 64 + kx] = lb;
}

// ---------------- Kernel D: 3x3 conv via MFMA (R10 structure, 64-pix blocks) --------
// grid 1024 (XCD-chunk swizzled): block -> (b, row y, col-half), 64 pix.
// 16 ksteps of K=64 (4 ci), single-buffered, inline staging (no reg arrays across
// barriers -> no scratch). Wave wv owns pix [16wv,16wv+16); 4 co-tiles per wave.
__global__ __launch_bounds__(256) void conv_kernel(const unsigned int* __restrict__ aohl,
                                                   const unsigned short* __restrict__ wfrag,
                                                   const float* __restrict__ bias,
                                                   float* __restrict__ out) {
    const int bid = blockIdx.x;
    const int swz = (bid & 7) * 128 + (bid >> 3);   // XCD-chunked: 128 consecutive per XCD
    const int b = swz >> 8;
    const int rem = swz & 255;
    const int y = rem >> 1;
    const int colbase = (rem & 1) * 64;
    const int tid = threadIdx.x;
    const int lane = tid & 63;
    const int wv = tid >> 6;
    const int rl = lane & 15;
    const int g  = lane >> 4;

    __shared__ unsigned short plds[2 * 64 * 64];   // 16384 B [hl][pix][k]
    __shared__ unsigned short wlds[2 * 64 * 64];   // 16384 B [hl][co][k]

    f32x4 acc[4];
#pragma unroll
    for (int ct = 0; ct < 4; ++ct) acc[ct] = (f32x4)0.f;

    const unsigned int* aob = aohl + (size_t)b * 64 * LL;
    const int spix = tid & 63;       // staging pixel (local)
    const int scis = tid >> 6;       // staging ci-select 0..3

    for (int ks = 0; ks < 16; ++ks) {
        __syncthreads();   // previous kstep's MFMA reads done
        // ---- stage W: 16 KB linear copy (fragment order pre-baked by wprep) ----
        {
            const uint4* wsrc = (const uint4*)(wfrag + (size_t)ks * 8192);
            uint4* wdst = (uint4*)&wlds[0];
#pragma unroll
            for (int i = 0; i < 4; ++i) wdst[i * 256 + tid] = wsrc[i * 256 + tid];
        }
        // ---- stage P: 64 pix x 4 ci, one slot per thread, inline ----
        {
            const int ci = ks * 4 + scis;
            const unsigned int* src = aob + (size_t)ci * LL;
            unsigned int p9[9];
#pragma unroll
            for (int dy = 0; dy < 3; ++dy) {
                const int yy = y + dy - 1;
#pragma unroll
                for (int dx = 0; dx < 3; ++dx) {
                    const int xx = colbase + spix + dx - 1;
                    const bool ok = (yy >= 0 && yy < HH && xx >= 0 && xx < WW);
                    p9[dy * 3 + dx] = ok ? src[yy * WW + xx] : 0u;
                }
            }
            unsigned short h16[16], l16[16];
#pragma unroll
            for (int j = 0; j < 16; ++j) {
                const unsigned int pv = (j < 9) ? p9[j] : 0u;
                h16[j] = (unsigned short)(pv & 0xffffu);
                l16[j] = (unsigned short)(pv >> 16);
            }
            const int x0 = (((2 * scis)     ^ (spix & 7)) << 3);
            const int x1 = (((2 * scis + 1) ^ (spix & 7)) << 3);
            *(u16x8*)&plds[(0 * 64 + spix) * 64 + x0] = *(u16x8*)&h16[0];
            *(u16x8*)&plds[(0 * 64 + spix) * 64 + x1] = *(u16x8*)&h16[8];
            *(u16x8*)&plds[(1 * 64 + spix) * 64 + x0] = *(u16x8*)&l16[0];
            *(u16x8*)&plds[(1 * 64 + spix) * 64 + x1] = *(u16x8*)&l16[8];
        }
        __syncthreads();

        // ---- MFMA: 2 ksubs x 4 co-tiles x 3 (hi/lo) ----
#pragma unroll
        for (int ksub = 0; ksub < 2; ++ksub) {
            const int xs = (((ksub * 4 + g) ^ (rl & 7)) << 3);
            const int row = wv * 16 + rl;
            const f16x8 bh = *(const f16x8*)&plds[(0 * 64 + row) * 64 + xs];
            const f16x8 bl = *(const f16x8*)&plds[(1 * 64 + row) * 64 + xs];
#pragma unroll
            for (int ct = 0; ct < 4; ++ct) {
                const int rowa = ct * 16 + rl;
                const f16x8 ah = *(const f16x8*)&wlds[(0 * 64 + rowa) * 64 + xs];
                const f16x8 al = *(const f16x8*)&wlds[(1 * 64 + rowa) * 64 + xs];
                acc[ct] = __builtin_amdgcn_mfma_f32_16x16x32_f16(ah, bh, acc[ct], 0, 0, 0);
                acc[ct] = __builtin_amdgcn_mfma_f32_16x16x32_f16(ah, bl, acc[ct], 0, 0, 0);
                acc[ct] = __builtin_amdgcn_mfma_f32_16x16x32_f16(al, bh, acc[ct], 0, 0, 0);
            }
        }
    }

#pragma unroll
    for (int ct = 0; ct < 4; ++ct) {
        const int co_b = ct * 16 + g * 4;
        const int px = colbase + wv * 16 + rl;
#pragma unroll
        for (int j = 0; j < 4; ++j) {
            const int co = co_b + j;
            out[((size_t)b * 64 + co) * LL + y * WW + px] = acc[ct][j] + bias[co];
        }
    }
}

extern "C" void kernel_launch(void* const* d_in, const int* in_sizes, int n_in,
                              void* d_out, int out_size, void* d_ws, size_t ws_size,
                              hipStream_t stream) {
    const float* x      = (const float*)d_in[0];
    const float* qkv_w  = (const float*)d_in[1];
    const float* qkv_b  = (const float*)d_in[2];
    const float* proj_w = (const float*)d_in[3];
    const float* proj_b = (const float*)d_in[4];
    float* out = (float*)d_out;
    float* ws  = (float*)d_ws;

    const size_t n1 = (size_t)4 * 64 * LL;      // one B*C*L plane set
    float* qb   = ws;
    float* kb   = ws + n1;
    float* vb   = ws + 2 * n1;
    unsigned int* aohl = (unsigned int*)(ws + 3 * n1);
    float* KV   = ws + 4 * n1;                  // 4*8*8*9*8 = 18432 floats
    float* KS   = KV + 4 * 8 * 8 * 9 * 8;       // 4*8*8*9  = 2304 floats
    float* KVp  = KS + 4 * 8 * 8 * 9;           // 32*32*648 = 663552 floats
    unsigned short* wfrag = (unsigned short*)(KVp + (size_t)32 * KVCHUNKS * 648);  // 131072 halfs

    wprep_kernel<<<256, 256, 0, stream>>>(proj_w, wfrag);
    qkv_kernel<<<dim3(128, 4, 3), 256, 0, stream>>>(x, qkv_w, qkv_b, qb, kb, vb);
    kv_kernel<<<dim3(KVCHUNKS, NH, 4), 256, 0, stream>>>(kb, vb, KVp);
    kv_finalize<<<32, 256, 0, stream>>>(KVp, KV, KS);
    attn_kernel<<<dim3(128, NH, 4), 128, 0, stream>>>(qb, KV, KS, aohl);
    conv_kernel<<<1024, 256, 0, stream>>>(aohl, wfrag, proj_b, out);
}